// Round 5
// baseline (649.616 us; speedup 1.0000x reference)
//
#include <hip/hip_runtime.h>
#include <hip/hip_bf16.h>

// MHAGCN: x(4096,6,1024) f32 -> out(4096,6,256) f32. Internal bf16 + MFMA.
// R11: tail split. R10 counters: BIG 10-slice dispatch = 311us @ 828 TF
// (m248 template ceiling for K=1024, WRITE amplification fixed); total only
// -7us => the tail holds ~150-180us in mid5 (serial 3x scores_grp chains,
// latency-bound, 1024 blocks). Split: scores_all = ONE standalone launch,
// 3072 tiny blocks (12/CU) covering all 5 heads; mid_ax = softmax+A+Xa only.
// BIG / H' / HW / out4 untouched.

using bf16 = __hip_bfloat16;
using s16x8 = __attribute__((ext_vector_type(8))) short;
using f32x4 = __attribute__((ext_vector_type(4))) float;

#define AS1(p) ((__attribute__((address_space(1))) void*)((void*)(p)))
#define AS3(p) ((__attribute__((address_space(3))) void*)(p))

#if defined(__has_builtin)
#if __has_builtin(__builtin_amdgcn_global_load_lds)
#define HAVE_GLL 1
#endif
#endif

__device__ __forceinline__ float s2f(short s) {
  union { unsigned int u; float f; } c;
  c.u = ((unsigned int)(unsigned short)s) << 16;
  return c.f;
}
__device__ __forceinline__ short f2s(float x) {
  bf16 b = __float2bfloat16(x);
  short s;
  __builtin_memcpy(&s, &b, 2);
  return s;
}

// GEMM output-routing job (selected per blockIdx.z)
struct GJob {
  const bf16* Bt;
  const float* bias;
  int boff;
  bf16* out;
};
struct GJobs10 {
  GJob j[10];
};

// ---------------------------------------------------------------------------
// prep: cvt x->bf16 (blocks [0,12288)) + 4 weight transposes ([12288,18048))
// ---------------------------------------------------------------------------
__global__ __launch_bounds__(256) void prep_kernel(
    const float* __restrict__ x, bf16* __restrict__ Xb,
    const float* __restrict__ aW1, bf16* __restrict__ W1T,
    const float* __restrict__ aW2, bf16* __restrict__ W2T,
    const float* __restrict__ gW1, bf16* __restrict__ G1T,
    const float* __restrict__ gW2, bf16* __restrict__ G2T) {
  const int bid = blockIdx.x, tid = threadIdx.x;
  if (bid < 12288) {
    int i = bid * 256 + tid;  // < 3145728
    float4 p0 = ((const float4*)x)[i * 2];
    float4 p1 = ((const float4*)x)[i * 2 + 1];
    s16x8 v;
    v[0] = f2s(p0.x); v[1] = f2s(p0.y); v[2] = f2s(p0.z); v[3] = f2s(p0.w);
    v[4] = f2s(p1.x); v[5] = f2s(p1.y); v[6] = f2s(p1.z); v[7] = f2s(p1.w);
    ((s16x8*)Xb)[i] = v;
    return;
  }
  int r = bid - 12288;
  const float* src; short* dst; int R, C, bx, by;
  if (r < 2560) {
    int z = r >> 9, q = r & 511;
    src = aW1 + (size_t)z * 524288; dst = (short*)W1T + (size_t)z * 524288;
    R = 1024; C = 512; bx = q & 31; by = q >> 5;
  } else if (r < 5120) {
    r -= 2560;
    int z = r >> 9, q = r & 511;
    src = aW2 + (size_t)z * 524288; dst = (short*)W2T + (size_t)z * 524288;
    R = 1024; C = 512; bx = q & 31; by = q >> 5;
  } else if (r < 5632) {
    r -= 5120;
    src = gW1; dst = (short*)G1T; R = 1024; C = 512; bx = r & 31; by = r >> 5;
  } else {
    r -= 5632;
    src = gW2; dst = (short*)G2T; R = 512; C = 256; bx = r & 15; by = r >> 4;
  }
  __shared__ short tile[32][33];
  const int tx = tid & 31, ty = tid >> 5;  // (32, 8)
  const int r0 = bx * 32, c0 = by * 32;
#pragma unroll
  for (int i = 0; i < 4; ++i)
    tile[ty + i * 8][tx] = f2s(src[(size_t)(r0 + ty + i * 8) * C + c0 + tx]);
  __syncthreads();
#pragma unroll
  for (int i = 0; i < 4; ++i)
    dst[(size_t)(c0 + ty + i * 8) * R + r0 + tx] = tile[tx][ty + i * 8];
}

// ---------------------------------------------------------------------------
// scores wave body (verified packing): rows {A: 0-7, B: 8-15} on BOTH m,n;
// valid outputs are the diagonal blocks. Serves batch-pair packing
// (standalone per-head) and head-pair packing (same batch, two heads).
// ---------------------------------------------------------------------------
__device__ __forceinline__ void scores_grp(
    const bf16* __restrict__ Qa, const bf16* __restrict__ Ka,
    const bf16* __restrict__ Qb, const bf16* __restrict__ Kb,
    int rowA, int rowB,            // global base row (x6 already applied)
    float* __restrict__ dstA, float* __restrict__ dstB,  // 6x6 each
    int lane) {
  const int l16 = lane & 15, quad = lane >> 4;
  int lr = l16 & 7; if (lr > 5) lr = 5;
  const int gr = ((l16 < 8) ? rowA : rowB) + lr;
  const short* qrow = (const short*)((l16 < 8) ? Qa : Qb) + (size_t)gr * 512 + quad * 8;
  const short* krow = (const short*)((l16 < 8) ? Ka : Kb) + (size_t)gr * 512 + quad * 8;

  f32x4 acc = (f32x4){0.f, 0.f, 0.f, 0.f};
#pragma unroll
  for (int kk = 0; kk < 16; ++kk) {
    s16x8 a = *(const s16x8*)(qrow + kk * 32);
    s16x8 b = *(const s16x8*)(krow + kk * 32);
    acc = __builtin_amdgcn_mfma_f32_16x16x32_bf16(a, b, acc, 0, 0, 0);
  }

  if (l16 < 6) {
#pragma unroll
    for (int r = 0; r < 4; ++r) {
      int m = quad * 4 + r;
      if (m < 6) dstA[m * 6 + l16] = acc[r];
    }
  } else if (l16 >= 8 && l16 < 14) {
#pragma unroll
    for (int r = 0; r < 4; ++r) {
      int m = quad * 4 + r;
      if (m >= 8 && m < 14) dstB[(m - 8) * 6 + (l16 - 8)] = acc[r];
    }
  }
}

// standalone scores (fallback path); up to 2 heads via blockIdx.y; per wave:
// 2 batches (rowA=b0*6, rowB=(b0+1)*6), writes straight to S.
__global__ __launch_bounds__(256) void scores_mfma2(
    const bf16* __restrict__ Q0, const bf16* __restrict__ KV0,
    const bf16* __restrict__ Q1, const bf16* __restrict__ KV1,
    float* __restrict__ S, int head0) {
  const int h = blockIdx.y;
  const bf16* Q = h ? Q1 : Q0;
  const bf16* KV = h ? KV1 : KV0;
  const int head = head0 + h;
  const int lane = threadIdx.x & 63, w = threadIdx.x >> 6;
  const int b0 = (blockIdx.x * 4 + w) * 2;
  scores_grp(Q, KV, Q, KV, b0 * 6, (b0 + 1) * 6,
             S + ((size_t)b0 * 5 + head) * 36,
             S + ((size_t)(b0 + 1) * 5 + head) * 36, lane);
}

// all-5-heads scores in ONE launch: grid (1024, 3); block = 4 waves = 4
// batches; blockIdx.y = head-pair (0,1),(2,3),(4,4). Head-pair packing
// (verified in R10's mid5): rows {headA b, headB b}; p=2 writes head 4
// twice to the same address (identical values, benign).
__global__ __launch_bounds__(256) void scores_all(
    const bf16* __restrict__ Q0, const bf16* __restrict__ K0,
    const bf16* __restrict__ Q1, const bf16* __restrict__ K1,
    const bf16* __restrict__ Q2, const bf16* __restrict__ K2,
    const bf16* __restrict__ Q3, const bf16* __restrict__ K3,
    const bf16* __restrict__ Q4, const bf16* __restrict__ K4,
    float* __restrict__ S) {
  const int p = blockIdx.y;
  const int g = threadIdx.x >> 6, t = threadIdx.x & 63;
  const int b = blockIdx.x * 4 + g;
  const int r6 = b * 6;
  const bf16 *Qa, *Ka, *Qb, *Kb;
  int ha, hb;
  if (p == 0)      { Qa = Q0; Ka = K0; Qb = Q1; Kb = K1; ha = 0; hb = 1; }
  else if (p == 1) { Qa = Q2; Ka = K2; Qb = Q3; Kb = K3; ha = 2; hb = 3; }
  else             { Qa = Q4; Ka = K4; Qb = Q4; Kb = K4; ha = 4; hb = 4; }
  scores_grp(Qa, Ka, Qb, Kb, r6, r6,
             S + ((size_t)b * 5 + ha) * 36,
             S + ((size_t)b * 5 + hb) * 36, t);
}

// ---------------------------------------------------------------------------
// Legacy 128x128 GEMM (m97 structure) — used for the HW gemm (N=256:
// (192,2)=384 light blocks beat 96 blocks of 256^2).
// ---------------------------------------------------------------------------
template <int AF32>
__global__ __launch_bounds__(256) void gemm_bt(
    const void* __restrict__ Ag,
    const bf16* __restrict__ Bt0, const bf16* __restrict__ Bt1,
    const float* __restrict__ bias0, const float* __restrict__ bias1, int boff,
    bf16* __restrict__ out0, bf16* __restrict__ out1,
    int M, int N, int K) {
  const bf16* Bt = (blockIdx.z == 0) ? Bt0 : Bt1;
  const float* bias = (blockIdx.z == 0) ? bias0 : bias1;
  bf16* Cg = (blockIdx.z == 0) ? out0 : out1;

  __shared__ short lA[128 * 32];
  __shared__ short lB[128 * 32];

  const int tid = threadIdx.x;
  const int lane = tid & 63, w = tid >> 6;
  const int wr = w >> 1, wc = w & 1;
  const int l16 = lane & 15, quad = lane >> 4;
  const int lrow = lane >> 2;
  const int scol = (((lane & 3) ^ ((lane >> 3) & 3)) * 8);

  const size_t rm0 = (size_t)blockIdx.x * 128;
  const size_t cn0 = (size_t)blockIdx.y * 128;

  f32x4 acc[4][4];
#pragma unroll
  for (int i = 0; i < 4; ++i)
#pragma unroll
    for (int j = 0; j < 4; ++j) acc[i][j] = (f32x4){0.f, 0.f, 0.f, 0.f};

  for (int kb = 0; kb < K; kb += 32) {
#pragma unroll
    for (int t = 0; t < 2; ++t) {
      int chunk = w * 2 + t;
      int row = chunk * 16 + lrow;
      const bf16* gb = Bt + (cn0 + row) * (size_t)K + kb + scol;
#ifdef HAVE_GLL
      __builtin_amdgcn_global_load_lds(AS1(gb), AS3(lB + chunk * 512), 16, 0, 0);
#else
      *(s16x8*)(lB + chunk * 512 + lane * 8) = *(const s16x8*)gb;
#endif
      if (AF32) {
        const float* ga = (const float*)Ag + (rm0 + row) * (size_t)K + kb + scol;
        float4 p0 = *(const float4*)ga;
        float4 p1 = *(const float4*)(ga + 4);
        s16x8 v;
        v[0] = f2s(p0.x); v[1] = f2s(p0.y); v[2] = f2s(p0.z); v[3] = f2s(p0.w);
        v[4] = f2s(p1.x); v[5] = f2s(p1.y); v[6] = f2s(p1.z); v[7] = f2s(p1.w);
        *(s16x8*)(lA + chunk * 512 + lane * 8) = v;
      } else {
        const bf16* ga = (const bf16*)Ag + (rm0 + row) * (size_t)K + kb + scol;
#ifdef HAVE_GLL
        __builtin_amdgcn_global_load_lds(AS1(ga), AS3(lA + chunk * 512), 16, 0, 0);
#else
        *(s16x8*)(lA + chunk * 512 + lane * 8) = *(const s16x8*)ga;
#endif
      }
    }
    __syncthreads();

    const int q2 = (quad ^ ((l16 >> 1) & 3)) * 8;
    s16x8 af[4], bfv[4];
#pragma unroll
    for (int i = 0; i < 4; ++i) {
      af[i] = *(const s16x8*)(lA + (wr * 64 + i * 16 + l16) * 32 + q2);
      bfv[i] = *(const s16x8*)(lB + (wc * 64 + i * 16 + l16) * 32 + q2);
    }
#pragma unroll
    for (int i = 0; i < 4; ++i)
#pragma unroll
      for (int j = 0; j < 4; ++j)
        acc[i][j] = __builtin_amdgcn_mfma_f32_16x16x32_bf16(af[i], bfv[j], acc[i][j], 0, 0, 0);
    __syncthreads();
  }

#pragma unroll
  for (int j = 0; j < 4; ++j) {
    size_t col = cn0 + wc * 64 + j * 16 + l16;
    float bv = bias ? bias[boff + col] : 0.f;
#pragma unroll
    for (int i = 0; i < 4; ++i) {
      size_t rowb = rm0 + wr * 64 + i * 16 + quad * 4;
#pragma unroll
      for (int r = 0; r < 4; ++r) {
        float v = acc[i][j][r] + bv;
        Cg[(rowb + r) * (size_t)N + col] = __float2bfloat16(v);
      }
    }
  }
}

// ---------------------------------------------------------------------------
// 256x256 8-phase GEMM (m201 template). Inner loop identical to R7-R10
// (verified). Per-z GJob array (up to 10 slices), optional fused
// bias+PReLU+BN1 epilogue (epi_z), LDS-staged coalesced output stores.
// ---------------------------------------------------------------------------
__global__ __launch_bounds__(512, 2) void gemm256_8ph(
    const bf16* __restrict__ A, GJobs10 jobs, int epi_z,
    const float* __restrict__ prelu_p,
    const float* __restrict__ bn_g, const float* __restrict__ bn_b,
    const float* __restrict__ bn_m, const float* __restrict__ bn_v,
    int M, int N, int K) {
  const GJob jb = jobs.j[blockIdx.z];
  const bf16* Bt = jb.Bt;
  const float* bias = jb.bias;
  const int boff = jb.boff;
  bf16* Cg = jb.out;
  const bool EPI = (epi_z == (int)blockIdx.z);

  __shared__ __attribute__((aligned(16))) short ldsS[65536];  // 128 KiB
  __shared__ float epi_s[12];

  const int tid = threadIdx.x;
  const int w = tid >> 6, l = tid & 63;
  const int l16 = l & 15, quad = l >> 4;
  const int wr = w >> 2, wc = w & 3;

  if (EPI && tid < 6) {
    float s = bn_g[tid] * rsqrtf(bn_v[tid] + 1e-5f);
    epi_s[tid] = s;
    epi_s[6 + tid] = bn_b[tid] - bn_m[tid] * s;
  }

  const size_t rm0 = (size_t)blockIdx.x * 256;
  const size_t cn0 = (size_t)blockIdx.y * 256;

  const int colS = ((l & 7) ^ (l >> 3)) * 8;       // shorts
  const int rowS = w * 16 + (l >> 3);              // + g*8 + h*128
  const short* pAs = (const short*)A + (rm0 + rowS) * (size_t)K + colS;
  const short* pBs = (const short*)Bt + (cn0 + rowS) * (size_t)K + colS;

  const int u0 = (quad ^ (l16 & 7)) * 8;
  const int u1 = ((quad + 4) ^ (l16 & 7)) * 8;

  f32x4 acc[8][4];
#pragma unroll
  for (int i = 0; i < 8; ++i)
#pragma unroll
    for (int j2i = 0; j2i < 4; ++j2i) acc[i][j2i] = (f32x4){0.f, 0.f, 0.f, 0.f};

  s16x8 af[4][2], bf0[2][2], bf1[2][2];

  const int T = K >> 6;  // K-tiles of 64

#ifdef HAVE_GLL
#define SA(BUF, H, KB) do {                                                          \
    __builtin_amdgcn_global_load_lds(AS1(pAs + (size_t)((H) * 128) * K + (KB)),      \
        AS3(ldsS + (BUF) * 32768 + (H) * 8192 + w * 1024), 16, 0, 0);                \
    __builtin_amdgcn_global_load_lds(AS1(pAs + (size_t)((H) * 128 + 8) * K + (KB)),  \
        AS3(ldsS + (BUF) * 32768 + (H) * 8192 + w * 1024 + 512), 16, 0, 0);          \
  } while (0)
#define SB(BUF, H, KB) do {                                                          \
    __builtin_amdgcn_global_load_lds(AS1(pBs + (size_t)((H) * 128) * K + (KB)),      \
        AS3(ldsS + (BUF) * 32768 + 16384 + (H) * 8192 + w * 1024), 16, 0, 0);        \
    __builtin_amdgcn_global_load_lds(AS1(pBs + (size_t)((H) * 128 + 8) * K + (KB)),  \
        AS3(ldsS + (BUF) * 32768 + 16384 + (H) * 8192 + w * 1024 + 512), 16, 0, 0);  \
  } while (0)
#else
#define SA(BUF, H, KB) do {                                                          \
    *(s16x8*)(ldsS + (BUF) * 32768 + (H) * 8192 + w * 1024 + l * 8) =                \
        *(const s16x8*)(pAs + (size_t)((H) * 128) * K + (KB));                       \
    *(s16x8*)(ldsS + (BUF) * 32768 + (H) * 8192 + w * 1024 + 512 + l * 8) =          \
        *(const s16x8*)(pAs + (size_t)((H) * 128 + 8) * K + (KB));                   \
  } while (0)
#define SB(BUF, H, KB) do {                                                          \
    *(s16x8*)(ldsS + (BUF) * 32768 + 16384 + (H) * 8192 + w * 1024 + l * 8) =        \
        *(const s16x8*)(pBs + (size_t)((H) * 128) * K + (KB));                       \
    *(s16x8*)(ldsS + (BUF) * 32768 + 16384 + (H) * 8192 + w * 1024 + 512 + l * 8) =  \
        *(const s16x8*)(pBs + (size_t)((H) * 128 + 8) * K + (KB));                   \
  } while (0)
#endif

#define LDA(BUF, MH) do {                                                            \
    _Pragma("unroll") for (int i = 0; i < 4; ++i) {                                  \
      const short* bse = ldsS + (BUF) * 32768 + wr * 8192 + (MH) * 4096 +            \
                         i * 1024 + l16 * 64;                                        \
      af[i][0] = *(const s16x8*)(bse + u0);                                          \
      af[i][1] = *(const s16x8*)(bse + u1);                                          \
    }                                                                                \
  } while (0)

#define LDB(BUF, NH, DST) do {                                                       \
    _Pragma("unroll") for (int n = 0; n < 2; ++n) {                                  \
      const short* bse = ldsS + (BUF) * 32768 + 16384 + (wc >> 1) * 8192 +           \
                         (wc & 1) * 4096 + (NH) * 2048 + n * 1024 + l16 * 64;        \
      DST[n][0] = *(const s16x8*)(bse + u0);                                         \
      DST[n][1] = *(const s16x8*)(bse + u1);                                         \
    }                                                                                \
  } while (0)

#define MFMAQ(MH, NH, BSET) do {                                                     \
    _Pragma("unroll") for (int i = 0; i < 4; ++i)                                    \
      _Pragma("unroll") for (int n = 0; n < 2; ++n) {                                \
        acc[(MH) * 4 + i][(NH) * 2 + n] = __builtin_amdgcn_mfma_f32_16x16x32_bf16(   \
            af[i][0], BSET[n][0], acc[(MH) * 4 + i][(NH) * 2 + n], 0, 0, 0);         \
        acc[(MH) * 4 + i][(NH) * 2 + n] = __builtin_amdgcn_mfma_f32_16x16x32_bf16(   \
            af[i][1], BSET[n][1], acc[(MH) * 4 + i][(NH) * 2 + n], 0, 0, 0);         \
      }                                                                              \
  } while (0)

#define BARX() asm volatile("s_barrier" ::: "memory")
#define LGKM0() do { asm volatile("s_waitcnt lgkmcnt(0)" ::: "memory");              \
                     __builtin_amdgcn_sched_barrier(0); } while (0)
#define VM6() do { asm volatile("s_waitcnt vmcnt(6)" ::: "memory");                  \
                   __builtin_amdgcn_sched_barrier(0); } while (0)

#define TILE_STEP(BUF, t) do {                                                       \
    const int kN_ = ((t) + 1 < T ? (t) + 1 : T - 1) << 6;                            \
    const int k2_ = ((t) + 2 < T ? (t) + 2 : T - 1) << 6;                            \
    /* ph0: all A(mh0) + all B reads; stage next tile's Ah1 (other buf) */           \
    LDA(BUF, 0); LDB(BUF, 0, bf0); LDB(BUF, 1, bf1);                                 \
    SA((BUF) ^ 1, 1, kN_);                                                           \
    BARX(); LGKM0();                                                                 \
    __builtin_amdgcn_s_setprio(1); MFMAQ(0, 0, bf0); __builtin_amdgcn_s_setprio(0);  \
    BARX();                                                                          \
    /* ph1: B slots of this buf are read-done -> stage t+2 Bh0 */                    \
    SB(BUF, 0, k2_);                                                                 \
    BARX();                                                                          \
    __builtin_amdgcn_s_setprio(1); MFMAQ(0, 1, bf1); __builtin_amdgcn_s_setprio(0);  \
    BARX();                                                                          \
    /* ph2: A(mh1) reads; stage t+2 Bh1 */                                           \
    LDA(BUF, 1);                                                                     \
    SB(BUF, 1, k2_);                                                                 \
    BARX(); LGKM0();                                                                 \
    __builtin_amdgcn_s_setprio(1); MFMAQ(1, 1, bf1); __builtin_amdgcn_s_setprio(0);  \
    BARX();                                                                          \
    /* ph3: A-half0 read-done -> stage t+2 Ah0; counted drain */                     \
    SA(BUF, 0, k2_);                                                                 \
    VM6();                                                                           \
    BARX();                                                                          \
    __builtin_amdgcn_s_setprio(1); MFMAQ(1, 0, bf0); __builtin_amdgcn_s_setprio(0);  \
    BARX();                                                                          \
  } while (0)

  // prologue: tile0 fully + tile1 {Bh0,Bh1,Ah0}; vmcnt(6) -> tile0 landed
  {
    const int k1_ = (T > 1 ? 1 : 0) << 6;
    SB(0, 0, 0); SB(0, 1, 0); SA(0, 0, 0); SA(0, 1, 0);
    SB(1, 0, k1_); SB(1, 1, k1_); SA(1, 0, k1_);
    VM6();
    BARX();
  }

  for (int t = 0; t < T; t += 2) {
    TILE_STEP(0, t);
    TILE_STEP(1, t + 1);
  }

  // ---- epilogue: stage wave's 128x64 bf16 tile in private LDS, then
  // coalesced 16B/lane stores. D row = quad*4+r, col = l16 (m89-verified).
  float pa = EPI ? prelu_p[0] : 0.f;
  short* st = ldsS + w * 8192;
#pragma unroll
  for (int jj = 0; jj < 4; ++jj) {
    int coll = jj * 16 + l16;
    float bv = bias ? bias[boff + (int)cn0 + wc * 64 + coll] : 0.f;
#pragma unroll
    for (int i = 0; i < 8; ++i) {
#pragma unroll
      for (int r = 0; r < 4; ++r) {
        int rowl = i * 16 + quad * 4 + r;
        float v = acc[i][jj][r] + bv;
        if (EPI) {
          v = (v >= 0.f) ? v : pa * v;
          int c = (int)((rm0 + wr * 128 + rowl) % 6);
          v = v * epi_s[c] + epi_s[6 + c];
        }
        st[rowl * 64 + coll] = f2s(v);
      }
    }
  }
  __syncthreads();
#pragma unroll
  for (int it = 0; it < 16; ++it) {
    int rowl = it * 8 + (l >> 3);
    int cch = (l & 7) * 8;
    s16x8 vv = *(const s16x8*)(st + rowl * 64 + cch);
    *(s16x8*)((short*)Cg + (rm0 + wr * 128 + rowl) * (size_t)N +
              cn0 + wc * 64 + cch) = vv;
  }
#undef SA
#undef SB
#undef LDA
#undef LDB
#undef MFMAQ
#undef BARX
#undef LGKM0
#undef VM6
#undef TILE_STEP
}

// ---------------------------------------------------------------------------
// mid_ax: 4 batches per 256-thr block (wave g <-> batch b). Reads S (L2/L3
// resident), per-head softmax -> cat@linW+linb -> softmax -> A (to Afull),
// Xa = A @ x written IN-PLACE into Xb (block-private rows).
// ---------------------------------------------------------------------------
__global__ __launch_bounds__(256) void mid_ax(
    const float* __restrict__ S, bf16* __restrict__ Xb,
    const float* __restrict__ linW, const float* __restrict__ linb,
    float* __restrict__ Afull) {
  const int tid = threadIdx.x, g = tid >> 6, t = tid & 63;
  const int b = blockIdx.x * 4 + g;
  __shared__ float p[4][5][6][6];
  __shared__ float Ar[4][6][6];
  __shared__ float lw[30][6];
  __shared__ float lbv[6];

  if (tid < 30) {
#pragma unroll
    for (int j = 0; j < 6; ++j) lw[tid][j] = linW[tid * 6 + j];
  }
  if (tid < 6) lbv[tid] = linb[tid];

  if (t < 36) {
#pragma unroll
    for (int k = 0; k < 5; ++k)
      p[g][k][t / 6][t % 6] = S[((size_t)b * 5 + k) * 36 + t];
  }
  __syncthreads();

  if (t < 30) {  // per (k,c): softmax over d, in place
    int k = t / 6, c = t % 6;
    float v[6];
#pragma unroll
    for (int d = 0; d < 6; ++d) v[d] = p[g][k][c][d];
    float mx = v[0];
#pragma unroll
    for (int d = 1; d < 6; ++d) mx = fmaxf(mx, v[d]);
    float s = 0.f;
#pragma unroll
    for (int d = 0; d < 6; ++d) { v[d] = expf(v[d] - mx); s += v[d]; }
    float inv = 1.f / s;
#pragma unroll
    for (int d = 0; d < 6; ++d) p[g][k][c][d] = v[d] * inv;
  }
  __syncthreads();

  if (t < 6) {
    int c = t;
    float ap[6];
#pragma unroll
    for (int j = 0; j < 6; ++j) ap[j] = lbv[j];
    for (int k = 0; k < 5; ++k)
#pragma unroll
      for (int d = 0; d < 6; ++d) {
        float pv = p[g][k][c][d];
#pragma unroll
        for (int j = 0; j < 6; ++j) ap[j] += pv * lw[k * 6 + d][j];
      }
    float mx = ap[0];
#pragma unroll
    for (int j = 1; j < 6; ++j) mx = fmaxf(mx, ap[j]);
    float s = 0.f;
#pragma unroll
    for (int j = 0; j < 6; ++j) { ap[j] = expf(ap[j] - mx); s += ap[j]; }
    float inv = 1.f / s;
#pragma unroll
    for (int j = 0; j < 6; ++j) {
      float a = ap[j] * inv;
      Ar[g][c][j] = a;
      Afull[(size_t)b * 36 + c * 6 + j] = a;
    }
  }
  __syncthreads();

  // Xa = A @ x, in place into Xb. Thread t reads all 6 rows at its cols,
  // then writes all 6 rows at the same cols: race-free (rows block-private,
  // cols thread-private, reads precede writes within thread).
  const int r6 = b * 6;
  short* xp = (short*)Xb;
#pragma unroll
  for (int it = 0; it < 2; ++it) {
    int c8 = (it * 64 + t) * 8;
    s16x8 xv[6];
#pragma unroll
    for (int d = 0; d < 6; ++d)
      xv[d] = *(const s16x8*)(xp + ((size_t)r6 + d) * 1024 + c8);
#pragma unroll
    for (int c = 0; c < 6; ++c) {
      s16x8 o;
#pragma unroll
      for (int e = 0; e < 8; ++e) {
        float s = 0.f;
#pragma unroll
        for (int d = 0; d < 6; ++d) s += Ar[g][c][d] * s2f(xv[d][e]);
        o[e] = f2s(s);
      }
      *(s16x8*)(xp + ((size_t)r6 + c) * 1024 + c8) = o;
    }
  }
}

// ---------------------------------------------------------------------------
// batch_out4: 4 batches per 256-thr block. out(f32) = BN2(A @ hw + gb2)
// ---------------------------------------------------------------------------
__global__ __launch_bounds__(256) void batch_out4(
    const float* __restrict__ Afull, const bf16* __restrict__ HW,
    const float* __restrict__ gb2,
    const float* __restrict__ g2, const float* __restrict__ b2,
    const float* __restrict__ m2, const float* __restrict__ v2,
    float* __restrict__ out) {
  const int tid = threadIdx.x, g = tid >> 6, t = tid & 63;
  const int b = blockIdx.x * 4 + g;
  __shared__ float Ar[4][36];
  __shared__ float sc[6], sm[6], sb[6];
  if (t < 36) Ar[g][t] = Afull[(size_t)b * 36 + t];
  if (tid < 6) {
    sc[tid] = g2[tid] * rsqrtf(v2[tid] + 1e-5f);
    sm[tid] = m2[tid];
    sb[tid] = b2[tid];
  }
  __syncthreads();
  for (int col = t; col < 256; col += 64) {
    float hw[6];
#pragma unroll
    for (int d = 0; d < 6; ++d) hw[d] = s2f(((const short*)HW)[((size_t)b * 6 + d) * 256 + col]);
    float gv = gb2[col];
#pragma unroll
    for (int c = 0; c < 6; ++c) {
      float o = gv;
#pragma unroll
      for (int d = 0; d < 6; ++d) o += Ar[g][c * 6 + d] * hw[d];
      o = (o - sm[c]) * sc[c] + sb[c];
      out[((size_t)b * 6 + c) * 256 + col] = o;
    }
  }
}

// ---------------------------------------------------------------------------
extern "C" void kernel_launch(void* const* d_in, const int* in_sizes, int n_in,
                              void* d_out, int out_size, void* d_ws, size_t ws_size,
                              hipStream_t stream) {
  const float* x    = (const float*)d_in[0];
  const float* aW1  = (const float*)d_in[1];
  const float* ab1  = (const float*)d_in[2];
  const float* aW2  = (const float*)d_in[3];
  const float* ab2  = (const float*)d_in[4];
  const float* linW = (const float*)d_in[5];
  const float* linb = (const float*)d_in[6];
  const float* gW1  = (const float*)d_in[7];
  const float* gb1  = (const float*)d_in[8];
  const float* gW2  = (const float*)d_in[9];
  const float* gb2  = (const float*)d_in[10];
  const float* prelu = (const float*)d_in[11];
  const float* bn1g = (const float*)d_in[12];
  const float* bn1b = (const float*)d_in[13];
  const float* bn1m = (const float*)d_in[14];
  const float* bn1v = (const float*)d_in[15];
  const float* bn2g = (const float*)d_in[16];
  const float* bn2b = (const float*)d_in[17];
  const float* bn2m = (const float*)d_in[18];
  const float* bn2v = (const float*)d_in[19];

  char* ws = (char*)d_ws;
  bf16* W1T = (bf16*)(ws + 0);           // 5 x 512 x 1024
  bf16* W2T = (bf16*)(ws + 5242880);     // 5 x 512 x 1024
  bf16* G1T = (bf16*)(ws + 10485760);    // 512 x 1024
  bf16* G2T = (bf16*)(ws + 11534336);    // 256 x 512
  float* S  = (float*)(ws + 11796480);   // 4096 x 5 x 36
  float* Af = (float*)(ws + 14745600);   // 4096 x 36
  bf16* Xb  = (bf16*)(ws + 15335424);    // 24576 x 1024 (x bf16, then Xa=A@x)
#define PANEL(i) ((bf16*)(ws + 65667072 + (size_t)(i) * 25165824))  // 24576x512
  const bool big5 = ws_size >= 292159488ull;  // P8 exists
  // ws >= 266993664 (P0..P7 + Xb) proven by R9's big3 run.

  prep_kernel<<<18048, 256, 0, stream>>>(x, Xb, aW1, W1T, aW2, W2T, gW1, G1T, gW2, G2T);

  GJobs10 J{};

  if (big5) {
    // ---- ONE Q/KV dispatch: 10 slices (1920 blocks = 7.5 rounds) ----
    for (int h = 0; h < 4; ++h) {
      J.j[2 * h]     = GJob{W1T + (size_t)h * 524288, ab1, h * 512, PANEL(2 * h)};
      J.j[2 * h + 1] = GJob{W2T + (size_t)h * 524288, ab2, h * 512, PANEL(2 * h + 1)};
    }
    J.j[8] = GJob{W1T + 4 * 524288, ab1, 2048, (bf16*)d_out};  // Q4 -> d_out scratch
    J.j[9] = GJob{W2T + 4 * 524288, ab2, 2048, PANEL(8)};      // KV4
    gemm256_8ph<<<dim3(96, 2, 10), 512, 0, stream>>>(
        Xb, J, -1, nullptr, nullptr, nullptr, nullptr, nullptr, 24576, 512, 1024);

    // ---- scores: ONE high-occupancy launch, all 5 heads ----
    scores_all<<<dim3(1024, 3), 256, 0, stream>>>(
        PANEL(0), PANEL(1), PANEL(2), PANEL(3), PANEL(4), PANEL(5),
        PANEL(6), PANEL(7), (const bf16*)d_out, PANEL(8), S);

    // ---- mid: softmaxes + A + Xa in-place ----
    mid_ax<<<1024, 256, 0, stream>>>(S, Xb, linW, linb, Af);

    // ---- H' = Xa @ gW1 with fused gb1 + PReLU + BN1 -> P0 ----
    GJobs10 JH{};
    JH.j[0] = GJob{G1T, gb1, 0, PANEL(0)};
    gemm256_8ph<<<dim3(96, 2, 1), 512, 0, stream>>>(
        Xb, JH, 0, prelu, bn1g, bn1b, bn1m, bn1v, 24576, 512, 1024);

    // ---- HW = H @ gW2 -> P1 ----
    gemm_bt<0><<<dim3(192, 2, 1), 256, 0, stream>>>(
        PANEL(0), G2T, G2T, nullptr, nullptr, 0, PANEL(1), PANEL(1), 24576, 256, 512);

    batch_out4<<<1024, 256, 0, stream>>>(Af, PANEL(1), gb2, bn2g, bn2b, bn2m, bn2v,
                                         (float*)d_out);
  } else {
    // ---- fallback (proven ws >= 267 MB): pairs + standalone scores ----
    for (int h = 0; h < 2; ++h) {
      J.j[2 * h]     = GJob{W1T + (size_t)h * 524288, ab1, h * 512, PANEL(2 * h)};
      J.j[2 * h + 1] = GJob{W2T + (size_t)h * 524288, ab2, h * 512, PANEL(2 * h + 1)};
    }
    gemm256_8ph<<<dim3(96, 2, 4), 512, 0, stream>>>(
        Xb, J, -1, nullptr, nullptr, nullptr, nullptr, nullptr, 24576, 512, 1024);
    scores_mfma2<<<dim3(512, 2), 256, 0, stream>>>(
        PANEL(0), PANEL(1), PANEL(2), PANEL(3), S, 0);

    for (int h = 0; h < 2; ++h) {
      J.j[2 * h]     = GJob{W1T + (size_t)(h + 2) * 524288, ab1, (h + 2) * 512, PANEL(4 + 2 * h)};
      J.j[2 * h + 1] = GJob{W2T + (size_t)(h + 2) * 524288, ab2, (h + 2) * 512, PANEL(5 + 2 * h)};
    }
    gemm256_8ph<<<dim3(96, 2, 4), 512, 0, stream>>>(
        Xb, J, -1, nullptr, nullptr, nullptr, nullptr, nullptr, 24576, 512, 1024);
    scores_mfma2<<<dim3(512, 2), 256, 0, stream>>>(
        PANEL(4), PANEL(5), PANEL(6), PANEL(7), S, 2);

    // head 4 -> P0 (Q4), P1 (KV4); heads 0/1 panels dead after scores
    J.j[0] = GJob{W1T + 4 * 524288, ab1, 2048, PANEL(0)};
    J.j[1] = GJob{W2T + 4 * 524288, ab2, 2048, PANEL(1)};
    gemm256_8ph<<<dim3(96, 2, 2), 512, 0, stream>>>(
        Xb, J, -1, nullptr, nullptr, nullptr, nullptr, nullptr, 24576, 512, 1024);
    scores_mfma2<<<dim3(512, 1), 256, 0, stream>>>(
        PANEL(0), PANEL(1), PANEL(0), PANEL(1), S, 4);

    mid_ax<<<1024, 256, 0, stream>>>(S, Xb, linW, linb, Af);

    GJobs10 JH{};
    JH.j[0] = GJob{G1T, gb1, 0, PANEL(2)};
    gemm256_8ph<<<dim3(96, 2, 1), 512, 0, stream>>>(
        Xb, JH, 0, prelu, bn1g, bn1b, bn1m, bn1v, 24576, 512, 1024);

    gemm_bt<0><<<dim3(192, 2, 1), 256, 0, stream>>>(
        PANEL(2), G2T, G2T, nullptr, nullptr, 0, PANEL(3), PANEL(3), 24576, 256, 512);

    batch_out4<<<1024, 256, 0, stream>>>(Af, PANEL(3), gb2, bn2g, bn2b, bn2m, bn2v,
                                         (float*)d_out);
  }
#undef PANEL
}

// Round 6
// 645.355 us; speedup vs baseline: 1.0066x; 1.0066x over previous
//
#include <hip/hip_runtime.h>
#include <hip/hip_bf16.h>

// MHAGCN: x(4096,6,1024) f32 -> out(4096,6,256) f32. Internal bf16 + MFMA.
// R12: revert to R10 flow (best measured, mid fused, no S round-trip) with
// mid5p: 1024-thr blocks, all 12 (batch x head-pair) score jobs in parallel
// waves (R10's mid5 ran 3 groups serially per 64-lane wave), then
// softmax->A->Xa with 4x threads. R11 lesson: splitting scores into a
// standalone launch was -20us WORSE (memory-bound on the 250MB panel
// re-read + launch gap + S round-trip); fused + parallel is the right form.
// BIG / H' / HW / out4 / fallback untouched.
// Pre-committed read: total >= 620 => panel round-trip is the sink; next
// round fuses partial scores into BIG's epilogue (padded-row layout).

using bf16 = __hip_bfloat16;
using s16x8 = __attribute__((ext_vector_type(8))) short;
using f32x4 = __attribute__((ext_vector_type(4))) float;

#define AS1(p) ((__attribute__((address_space(1))) void*)((void*)(p)))
#define AS3(p) ((__attribute__((address_space(3))) void*)(p))

#if defined(__has_builtin)
#if __has_builtin(__builtin_amdgcn_global_load_lds)
#define HAVE_GLL 1
#endif
#endif

__device__ __forceinline__ float s2f(short s) {
  union { unsigned int u; float f; } c;
  c.u = ((unsigned int)(unsigned short)s) << 16;
  return c.f;
}
__device__ __forceinline__ short f2s(float x) {
  bf16 b = __float2bfloat16(x);
  short s;
  __builtin_memcpy(&s, &b, 2);
  return s;
}

// GEMM output-routing job (selected per blockIdx.z)
struct GJob {
  const bf16* Bt;
  const float* bias;
  int boff;
  bf16* out;
};
struct GJobs10 {
  GJob j[10];
};

// ---------------------------------------------------------------------------
// prep: cvt x->bf16 (blocks [0,12288)) + 4 weight transposes ([12288,18048))
// ---------------------------------------------------------------------------
__global__ __launch_bounds__(256) void prep_kernel(
    const float* __restrict__ x, bf16* __restrict__ Xb,
    const float* __restrict__ aW1, bf16* __restrict__ W1T,
    const float* __restrict__ aW2, bf16* __restrict__ W2T,
    const float* __restrict__ gW1, bf16* __restrict__ G1T,
    const float* __restrict__ gW2, bf16* __restrict__ G2T) {
  const int bid = blockIdx.x, tid = threadIdx.x;
  if (bid < 12288) {
    int i = bid * 256 + tid;  // < 3145728
    float4 p0 = ((const float4*)x)[i * 2];
    float4 p1 = ((const float4*)x)[i * 2 + 1];
    s16x8 v;
    v[0] = f2s(p0.x); v[1] = f2s(p0.y); v[2] = f2s(p0.z); v[3] = f2s(p0.w);
    v[4] = f2s(p1.x); v[5] = f2s(p1.y); v[6] = f2s(p1.z); v[7] = f2s(p1.w);
    ((s16x8*)Xb)[i] = v;
    return;
  }
  int r = bid - 12288;
  const float* src; short* dst; int R, C, bx, by;
  if (r < 2560) {
    int z = r >> 9, q = r & 511;
    src = aW1 + (size_t)z * 524288; dst = (short*)W1T + (size_t)z * 524288;
    R = 1024; C = 512; bx = q & 31; by = q >> 5;
  } else if (r < 5120) {
    r -= 2560;
    int z = r >> 9, q = r & 511;
    src = aW2 + (size_t)z * 524288; dst = (short*)W2T + (size_t)z * 524288;
    R = 1024; C = 512; bx = q & 31; by = q >> 5;
  } else if (r < 5632) {
    r -= 5120;
    src = gW1; dst = (short*)G1T; R = 1024; C = 512; bx = r & 31; by = r >> 5;
  } else {
    r -= 5632;
    src = gW2; dst = (short*)G2T; R = 512; C = 256; bx = r & 15; by = r >> 4;
  }
  __shared__ short tile[32][33];
  const int tx = tid & 31, ty = tid >> 5;  // (32, 8)
  const int r0 = bx * 32, c0 = by * 32;
#pragma unroll
  for (int i = 0; i < 4; ++i)
    tile[ty + i * 8][tx] = f2s(src[(size_t)(r0 + ty + i * 8) * C + c0 + tx]);
  __syncthreads();
#pragma unroll
  for (int i = 0; i < 4; ++i)
    dst[(size_t)(c0 + ty + i * 8) * R + r0 + tx] = tile[tx][ty + i * 8];
}

// ---------------------------------------------------------------------------
// scores wave body (verified packing): rows {A: 0-7, B: 8-15} on BOTH m,n;
// valid outputs are the diagonal blocks. Serves batch-pair packing
// (standalone per-head) and head-pair packing (same batch, two heads).
// ---------------------------------------------------------------------------
__device__ __forceinline__ void scores_grp(
    const bf16* __restrict__ Qa, const bf16* __restrict__ Ka,
    const bf16* __restrict__ Qb, const bf16* __restrict__ Kb,
    int rowA, int rowB,            // global base row (x6 already applied)
    float* __restrict__ dstA, float* __restrict__ dstB,  // 6x6 each
    int lane) {
  const int l16 = lane & 15, quad = lane >> 4;
  int lr = l16 & 7; if (lr > 5) lr = 5;
  const int gr = ((l16 < 8) ? rowA : rowB) + lr;
  const short* qrow = (const short*)((l16 < 8) ? Qa : Qb) + (size_t)gr * 512 + quad * 8;
  const short* krow = (const short*)((l16 < 8) ? Ka : Kb) + (size_t)gr * 512 + quad * 8;

  f32x4 acc = (f32x4){0.f, 0.f, 0.f, 0.f};
#pragma unroll
  for (int kk = 0; kk < 16; ++kk) {
    s16x8 a = *(const s16x8*)(qrow + kk * 32);
    s16x8 b = *(const s16x8*)(krow + kk * 32);
    acc = __builtin_amdgcn_mfma_f32_16x16x32_bf16(a, b, acc, 0, 0, 0);
  }

  if (l16 < 6) {
#pragma unroll
    for (int r = 0; r < 4; ++r) {
      int m = quad * 4 + r;
      if (m < 6) dstA[m * 6 + l16] = acc[r];
    }
  } else if (l16 >= 8 && l16 < 14) {
#pragma unroll
    for (int r = 0; r < 4; ++r) {
      int m = quad * 4 + r;
      if (m >= 8 && m < 14) dstB[(m - 8) * 6 + (l16 - 8)] = acc[r];
    }
  }
}

// standalone scores (fallback path); up to 2 heads via blockIdx.y; per wave:
// 2 batches (rowA=b0*6, rowB=(b0+1)*6), writes straight to S.
__global__ __launch_bounds__(256) void scores_mfma2(
    const bf16* __restrict__ Q0, const bf16* __restrict__ KV0,
    const bf16* __restrict__ Q1, const bf16* __restrict__ KV1,
    float* __restrict__ S, int head0) {
  const int h = blockIdx.y;
  const bf16* Q = h ? Q1 : Q0;
  const bf16* KV = h ? KV1 : KV0;
  const int head = head0 + h;
  const int lane = threadIdx.x & 63, w = threadIdx.x >> 6;
  const int b0 = (blockIdx.x * 4 + w) * 2;
  scores_grp(Q, KV, Q, KV, b0 * 6, (b0 + 1) * 6,
             S + ((size_t)b0 * 5 + head) * 36,
             S + ((size_t)(b0 + 1) * 5 + head) * 36, lane);
}

// ---------------------------------------------------------------------------
// Legacy 128x128 GEMM (m97 structure) — used for the HW gemm (N=256:
// (192,2)=384 light blocks beat 96 blocks of 256^2).
// ---------------------------------------------------------------------------
template <int AF32>
__global__ __launch_bounds__(256) void gemm_bt(
    const void* __restrict__ Ag,
    const bf16* __restrict__ Bt0, const bf16* __restrict__ Bt1,
    const float* __restrict__ bias0, const float* __restrict__ bias1, int boff,
    bf16* __restrict__ out0, bf16* __restrict__ out1,
    int M, int N, int K) {
  const bf16* Bt = (blockIdx.z == 0) ? Bt0 : Bt1;
  const float* bias = (blockIdx.z == 0) ? bias0 : bias1;
  bf16* Cg = (blockIdx.z == 0) ? out0 : out1;

  __shared__ short lA[128 * 32];
  __shared__ short lB[128 * 32];

  const int tid = threadIdx.x;
  const int lane = tid & 63, w = tid >> 6;
  const int wr = w >> 1, wc = w & 1;
  const int l16 = lane & 15, quad = lane >> 4;
  const int lrow = lane >> 2;
  const int scol = (((lane & 3) ^ ((lane >> 3) & 3)) * 8);

  const size_t rm0 = (size_t)blockIdx.x * 128;
  const size_t cn0 = (size_t)blockIdx.y * 128;

  f32x4 acc[4][4];
#pragma unroll
  for (int i = 0; i < 4; ++i)
#pragma unroll
    for (int j = 0; j < 4; ++j) acc[i][j] = (f32x4){0.f, 0.f, 0.f, 0.f};

  for (int kb = 0; kb < K; kb += 32) {
#pragma unroll
    for (int t = 0; t < 2; ++t) {
      int chunk = w * 2 + t;
      int row = chunk * 16 + lrow;
      const bf16* gb = Bt + (cn0 + row) * (size_t)K + kb + scol;
#ifdef HAVE_GLL
      __builtin_amdgcn_global_load_lds(AS1(gb), AS3(lB + chunk * 512), 16, 0, 0);
#else
      *(s16x8*)(lB + chunk * 512 + lane * 8) = *(const s16x8*)gb;
#endif
      if (AF32) {
        const float* ga = (const float*)Ag + (rm0 + row) * (size_t)K + kb + scol;
        float4 p0 = *(const float4*)ga;
        float4 p1 = *(const float4*)(ga + 4);
        s16x8 v;
        v[0] = f2s(p0.x); v[1] = f2s(p0.y); v[2] = f2s(p0.z); v[3] = f2s(p0.w);
        v[4] = f2s(p1.x); v[5] = f2s(p1.y); v[6] = f2s(p1.z); v[7] = f2s(p1.w);
        *(s16x8*)(lA + chunk * 512 + lane * 8) = v;
      } else {
        const bf16* ga = (const bf16*)Ag + (rm0 + row) * (size_t)K + kb + scol;
#ifdef HAVE_GLL
        __builtin_amdgcn_global_load_lds(AS1(ga), AS3(lA + chunk * 512), 16, 0, 0);
#else
        *(s16x8*)(lA + chunk * 512 + lane * 8) = *(const s16x8*)ga;
#endif
      }
    }
    __syncthreads();

    const int q2 = (quad ^ ((l16 >> 1) & 3)) * 8;
    s16x8 af[4], bfv[4];
#pragma unroll
    for (int i = 0; i < 4; ++i) {
      af[i] = *(const s16x8*)(lA + (wr * 64 + i * 16 + l16) * 32 + q2);
      bfv[i] = *(const s16x8*)(lB + (wc * 64 + i * 16 + l16) * 32 + q2);
    }
#pragma unroll
    for (int i = 0; i < 4; ++i)
#pragma unroll
      for (int j = 0; j < 4; ++j)
        acc[i][j] = __builtin_amdgcn_mfma_f32_16x16x32_bf16(af[i], bfv[j], acc[i][j], 0, 0, 0);
    __syncthreads();
  }

#pragma unroll
  for (int j = 0; j < 4; ++j) {
    size_t col = cn0 + wc * 64 + j * 16 + l16;
    float bv = bias ? bias[boff + col] : 0.f;
#pragma unroll
    for (int i = 0; i < 4; ++i) {
      size_t rowb = rm0 + wr * 64 + i * 16 + quad * 4;
#pragma unroll
      for (int r = 0; r < 4; ++r) {
        float v = acc[i][j][r] + bv;
        Cg[(rowb + r) * (size_t)N + col] = __float2bfloat16(v);
      }
    }
  }
}

// ---------------------------------------------------------------------------
// 256x256 8-phase GEMM (m201 template). Inner loop identical to R7-R11
// (verified). Per-z GJob array (up to 10 slices), optional fused
// bias+PReLU+BN1 epilogue (epi_z), LDS-staged coalesced output stores.
// ---------------------------------------------------------------------------
__global__ __launch_bounds__(512, 2) void gemm256_8ph(
    const bf16* __restrict__ A, GJobs10 jobs, int epi_z,
    const float* __restrict__ prelu_p,
    const float* __restrict__ bn_g, const float* __restrict__ bn_b,
    const float* __restrict__ bn_m, const float* __restrict__ bn_v,
    int M, int N, int K) {
  const GJob jb = jobs.j[blockIdx.z];
  const bf16* Bt = jb.Bt;
  const float* bias = jb.bias;
  const int boff = jb.boff;
  bf16* Cg = jb.out;
  const bool EPI = (epi_z == (int)blockIdx.z);

  __shared__ __attribute__((aligned(16))) short ldsS[65536];  // 128 KiB
  __shared__ float epi_s[12];

  const int tid = threadIdx.x;
  const int w = tid >> 6, l = tid & 63;
  const int l16 = l & 15, quad = l >> 4;
  const int wr = w >> 2, wc = w & 3;

  if (EPI && tid < 6) {
    float s = bn_g[tid] * rsqrtf(bn_v[tid] + 1e-5f);
    epi_s[tid] = s;
    epi_s[6 + tid] = bn_b[tid] - bn_m[tid] * s;
  }

  const size_t rm0 = (size_t)blockIdx.x * 256;
  const size_t cn0 = (size_t)blockIdx.y * 256;

  const int colS = ((l & 7) ^ (l >> 3)) * 8;       // shorts
  const int rowS = w * 16 + (l >> 3);              // + g*8 + h*128
  const short* pAs = (const short*)A + (rm0 + rowS) * (size_t)K + colS;
  const short* pBs = (const short*)Bt + (cn0 + rowS) * (size_t)K + colS;

  const int u0 = (quad ^ (l16 & 7)) * 8;
  const int u1 = ((quad + 4) ^ (l16 & 7)) * 8;

  f32x4 acc[8][4];
#pragma unroll
  for (int i = 0; i < 8; ++i)
#pragma unroll
    for (int j2i = 0; j2i < 4; ++j2i) acc[i][j2i] = (f32x4){0.f, 0.f, 0.f, 0.f};

  s16x8 af[4][2], bf0[2][2], bf1[2][2];

  const int T = K >> 6;  // K-tiles of 64

#ifdef HAVE_GLL
#define SA(BUF, H, KB) do {                                                          \
    __builtin_amdgcn_global_load_lds(AS1(pAs + (size_t)((H) * 128) * K + (KB)),      \
        AS3(ldsS + (BUF) * 32768 + (H) * 8192 + w * 1024), 16, 0, 0);                \
    __builtin_amdgcn_global_load_lds(AS1(pAs + (size_t)((H) * 128 + 8) * K + (KB)),  \
        AS3(ldsS + (BUF) * 32768 + (H) * 8192 + w * 1024 + 512), 16, 0, 0);          \
  } while (0)
#define SB(BUF, H, KB) do {                                                          \
    __builtin_amdgcn_global_load_lds(AS1(pBs + (size_t)((H) * 128) * K + (KB)),      \
        AS3(ldsS + (BUF) * 32768 + 16384 + (H) * 8192 + w * 1024), 16, 0, 0);        \
    __builtin_amdgcn_global_load_lds(AS1(pBs + (size_t)((H) * 128 + 8) * K + (KB)),  \
        AS3(ldsS + (BUF) * 32768 + 16384 + (H) * 8192 + w * 1024 + 512), 16, 0, 0);  \
  } while (0)
#else
#define SA(BUF, H, KB) do {                                                          \
    *(s16x8*)(ldsS + (BUF) * 32768 + (H) * 8192 + w * 1024 + l * 8) =                \
        *(const s16x8*)(pAs + (size_t)((H) * 128) * K + (KB));                       \
    *(s16x8*)(ldsS + (BUF) * 32768 + (H) * 8192 + w * 1024 + 512 + l * 8) =          \
        *(const s16x8*)(pAs + (size_t)((H) * 128 + 8) * K + (KB));                   \
  } while (0)
#define SB(BUF, H, KB) do {                                                          \
    *(s16x8*)(ldsS + (BUF) * 32768 + 16384 + (H) * 8192 + w * 1024 + l * 8) =        \
        *(const s16x8*)(pBs + (size_t)((H) * 128) * K + (KB));                       \
    *(s16x8*)(ldsS + (BUF) * 32768 + 16384 + (H) * 8192 + w * 1024 + 512 + l * 8) =  \
        *(const s16x8*)(pBs + (size_t)((H) * 128 + 8) * K + (KB));                   \
  } while (0)
#endif

#define LDA(BUF, MH) do {                                                            \
    _Pragma("unroll") for (int i = 0; i < 4; ++i) {                                  \
      const short* bse = ldsS + (BUF) * 32768 + wr * 8192 + (MH) * 4096 +            \
                         i * 1024 + l16 * 64;                                        \
      af[i][0] = *(const s16x8*)(bse + u0);                                          \
      af[i][1] = *(const s16x8*)(bse + u1);                                          \
    }                                                                                \
  } while (0)

#define LDB(BUF, NH, DST) do {                                                       \
    _Pragma("unroll") for (int n = 0; n < 2; ++n) {                                  \
      const short* bse = ldsS + (BUF) * 32768 + 16384 + (wc >> 1) * 8192 +           \
                         (wc & 1) * 4096 + (NH) * 2048 + n * 1024 + l16 * 64;        \
      DST[n][0] = *(const s16x8*)(bse + u0);                                         \
      DST[n][1] = *(const s16x8*)(bse + u1);                                         \
    }                                                                                \
  } while (0)

#define MFMAQ(MH, NH, BSET) do {                                                     \
    _Pragma("unroll") for (int i = 0; i < 4; ++i)                                    \
      _Pragma("unroll") for (int n = 0; n < 2; ++n) {                                \
        acc[(MH) * 4 + i][(NH) * 2 + n] = __builtin_amdgcn_mfma_f32_16x16x32_bf16(   \
            af[i][0], BSET[n][0], acc[(MH) * 4 + i][(NH) * 2 + n], 0, 0, 0);         \
        acc[(MH) * 4 + i][(NH) * 2 + n] = __builtin_amdgcn_mfma_f32_16x16x32_bf16(   \
            af[i][1], BSET[n][1], acc[(MH) * 4 + i][(NH) * 2 + n], 0, 0, 0);         \
      }                                                                              \
  } while (0)

#define BARX() asm volatile("s_barrier" ::: "memory")
#define LGKM0() do { asm volatile("s_waitcnt lgkmcnt(0)" ::: "memory");              \
                     __builtin_amdgcn_sched_barrier(0); } while (0)
#define VM6() do { asm volatile("s_waitcnt vmcnt(6)" ::: "memory");                  \
                   __builtin_amdgcn_sched_barrier(0); } while (0)

#define TILE_STEP(BUF, t) do {                                                       \
    const int kN_ = ((t) + 1 < T ? (t) + 1 : T - 1) << 6;                            \
    const int k2_ = ((t) + 2 < T ? (t) + 2 : T - 1) << 6;                            \
    /* ph0: all A(mh0) + all B reads; stage next tile's Ah1 (other buf) */           \
    LDA(BUF, 0); LDB(BUF, 0, bf0); LDB(BUF, 1, bf1);                                 \
    SA((BUF) ^ 1, 1, kN_);                                                           \
    BARX(); LGKM0();                                                                 \
    __builtin_amdgcn_s_setprio(1); MFMAQ(0, 0, bf0); __builtin_amdgcn_s_setprio(0);  \
    BARX();                                                                          \
    /* ph1: B slots of this buf are read-done -> stage t+2 Bh0 */                    \
    SB(BUF, 0, k2_);                                                                 \
    BARX();                                                                          \
    __builtin_amdgcn_s_setprio(1); MFMAQ(0, 1, bf1); __builtin_amdgcn_s_setprio(0);  \
    BARX();                                                                          \
    /* ph2: A(mh1) reads; stage t+2 Bh1 */                                           \
    LDA(BUF, 1);                                                                     \
    SB(BUF, 1, k2_);                                                                 \
    BARX(); LGKM0();                                                                 \
    __builtin_amdgcn_s_setprio(1); MFMAQ(1, 1, bf1); __builtin_amdgcn_s_setprio(0);  \
    BARX();                                                                          \
    /* ph3: A-half0 read-done -> stage t+2 Ah0; counted drain */                     \
    SA(BUF, 0, k2_);                                                                 \
    VM6();                                                                           \
    BARX();                                                                          \
    __builtin_amdgcn_s_setprio(1); MFMAQ(1, 0, bf0); __builtin_amdgcn_s_setprio(0);  \
    BARX();                                                                          \
  } while (0)

  // prologue: tile0 fully + tile1 {Bh0,Bh1,Ah0}; vmcnt(6) -> tile0 landed
  {
    const int k1_ = (T > 1 ? 1 : 0) << 6;
    SB(0, 0, 0); SB(0, 1, 0); SA(0, 0, 0); SA(0, 1, 0);
    SB(1, 0, k1_); SB(1, 1, k1_); SA(1, 0, k1_);
    VM6();
    BARX();
  }

  for (int t = 0; t < T; t += 2) {
    TILE_STEP(0, t);
    TILE_STEP(1, t + 1);
  }

  // ---- epilogue: stage wave's 128x64 bf16 tile in private LDS, then
  // coalesced 16B/lane stores. D row = quad*4+r, col = l16 (m89-verified).
  float pa = EPI ? prelu_p[0] : 0.f;
  short* st = ldsS + w * 8192;
#pragma unroll
  for (int jj = 0; jj < 4; ++jj) {
    int coll = jj * 16 + l16;
    float bv = bias ? bias[boff + (int)cn0 + wc * 64 + coll] : 0.f;
#pragma unroll
    for (int i = 0; i < 8; ++i) {
#pragma unroll
      for (int r = 0; r < 4; ++r) {
        int rowl = i * 16 + quad * 4 + r;
        float v = acc[i][jj][r] + bv;
        if (EPI) {
          v = (v >= 0.f) ? v : pa * v;
          int c = (int)((rm0 + wr * 128 + rowl) % 6);
          v = v * epi_s[c] + epi_s[6 + c];
        }
        st[rowl * 64 + coll] = f2s(v);
      }
    }
  }
  __syncthreads();
#pragma unroll
  for (int it = 0; it < 16; ++it) {
    int rowl = it * 8 + (l >> 3);
    int cch = (l & 7) * 8;
    s16x8 vv = *(const s16x8*)(st + rowl * 64 + cch);
    *(s16x8*)((short*)Cg + (rm0 + wr * 128 + rowl) * (size_t)N +
              cn0 + wc * 64 + cch) = vv;
  }
#undef SA
#undef SB
#undef LDA
#undef LDB
#undef MFMAQ
#undef BARX
#undef LGKM0
#undef VM6
#undef TILE_STEP
}

// ---------------------------------------------------------------------------
// mid5p: 1024 threads = 16 waves; 4 batches per block. Waves 0-11 compute
// the 12 (batch g, head-pair p) score jobs IN PARALLEL (R10's mid5 ran the
// 3 pairs serially per 64-lane wave). Then (4x threads) per-head softmax ->
// cat@linW+linb -> softmax -> A (to Afull), and Xa = A@x in place into Xb.
// ---------------------------------------------------------------------------
__global__ __launch_bounds__(1024) void mid5p(
    const bf16* __restrict__ Q0, const bf16* __restrict__ Q1,
    const bf16* __restrict__ Q2, const bf16* __restrict__ Q3,
    const bf16* __restrict__ K0, const bf16* __restrict__ K1,
    const bf16* __restrict__ K2, const bf16* __restrict__ K3,
    const bf16* __restrict__ Q4, const bf16* __restrict__ K4,
    bf16* __restrict__ Xb,
    const float* __restrict__ linW, const float* __restrict__ linb,
    float* __restrict__ Afull) {
  const int tid = threadIdx.x;
  const int w = tid >> 6, lane = tid & 63;
  const int b0 = blockIdx.x * 4;
  __shared__ float p[4][5][6][6];
  __shared__ float Ar[4][6][6];
  __shared__ float lw[30][6];
  __shared__ float lbv[6];

  if (tid < 30) {
#pragma unroll
    for (int j = 0; j < 6; ++j) lw[tid][j] = linW[tid * 6 + j];
  }
  if (tid >= 32 && tid < 38) lbv[tid - 32] = linb[tid - 32];

  if (w < 12) {  // parallel score jobs: g = w&3, pair = w>>2
    const int gg = w & 3, pp = w >> 2;
    const int r6 = (b0 + gg) * 6;
    const bf16 *Qa, *Ka, *Qb, *Kb;
    float *dA, *dB;
    if (pp == 0) { Qa = Q0; Ka = K0; Qb = Q1; Kb = K1;
                   dA = &p[gg][0][0][0]; dB = &p[gg][1][0][0]; }
    else if (pp == 1) { Qa = Q2; Ka = K2; Qb = Q3; Kb = K3;
                        dA = &p[gg][2][0][0]; dB = &p[gg][3][0][0]; }
    else { Qa = Q4; Ka = K4; Qb = Q4; Kb = K4;
           dA = &p[gg][4][0][0]; dB = dA; }
    scores_grp(Qa, Ka, Qb, Kb, r6, r6, dA, dB, lane);
  }
  __syncthreads();

  const int g = tid >> 8, t = tid & 255;
  const int b = b0 + g, r6 = b * 6;

  if (t < 30) {  // per (k,c): softmax over d, in place
    int k = t / 6, c = t % 6;
    float v[6];
#pragma unroll
    for (int d = 0; d < 6; ++d) v[d] = p[g][k][c][d];
    float mx = v[0];
#pragma unroll
    for (int d = 1; d < 6; ++d) mx = fmaxf(mx, v[d]);
    float s = 0.f;
#pragma unroll
    for (int d = 0; d < 6; ++d) { v[d] = expf(v[d] - mx); s += v[d]; }
    float inv = 1.f / s;
#pragma unroll
    for (int d = 0; d < 6; ++d) p[g][k][c][d] = v[d] * inv;
  }
  __syncthreads();

  if (t < 6) {
    int c = t;
    float ap[6];
#pragma unroll
    for (int j = 0; j < 6; ++j) ap[j] = lbv[j];
    for (int k = 0; k < 5; ++k)
#pragma unroll
      for (int d = 0; d < 6; ++d) {
        float pv = p[g][k][c][d];
#pragma unroll
        for (int j = 0; j < 6; ++j) ap[j] += pv * lw[k * 6 + d][j];
      }
    float mx = ap[0];
#pragma unroll
    for (int j = 1; j < 6; ++j) mx = fmaxf(mx, ap[j]);
    float s = 0.f;
#pragma unroll
    for (int j = 0; j < 6; ++j) { ap[j] = expf(ap[j] - mx); s += ap[j]; }
    float inv = 1.f / s;
#pragma unroll
    for (int j = 0; j < 6; ++j) {
      float a = ap[j] * inv;
      Ar[g][c][j] = a;
      Afull[(size_t)b * 36 + c * 6 + j] = a;
    }
  }
  __syncthreads();

  // Xa = A @ x, in place into Xb. Threads t<128 per g: col unit c8 = t*8.
  // Rows block-private, cols thread-private, reads precede writes: race-free.
  if (t < 128) {
    short* xp = (short*)Xb;
    int c8 = t * 8;
    s16x8 xv[6];
#pragma unroll
    for (int d = 0; d < 6; ++d)
      xv[d] = *(const s16x8*)(xp + ((size_t)r6 + d) * 1024 + c8);
#pragma unroll
    for (int c = 0; c < 6; ++c) {
      s16x8 o;
#pragma unroll
      for (int e = 0; e < 8; ++e) {
        float s = 0.f;
#pragma unroll
        for (int d = 0; d < 6; ++d) s += Ar[g][c][d] * s2f(xv[d][e]);
        o[e] = f2s(s);
      }
      *(s16x8*)(xp + ((size_t)r6 + c) * 1024 + c8) = o;
    }
  }
}

// ---------------------------------------------------------------------------
// mid_ax (fallback): 4 batches per 256-thr block; reads S, softmax -> A,
// Xa = A @ x in place.
// ---------------------------------------------------------------------------
__global__ __launch_bounds__(256) void mid_ax(
    const float* __restrict__ S, bf16* __restrict__ Xb,
    const float* __restrict__ linW, const float* __restrict__ linb,
    float* __restrict__ Afull) {
  const int tid = threadIdx.x, g = tid >> 6, t = tid & 63;
  const int b = blockIdx.x * 4 + g;
  __shared__ float p[4][5][6][6];
  __shared__ float Ar[4][6][6];
  __shared__ float lw[30][6];
  __shared__ float lbv[6];

  if (tid < 30) {
#pragma unroll
    for (int j = 0; j < 6; ++j) lw[tid][j] = linW[tid * 6 + j];
  }
  if (tid < 6) lbv[tid] = linb[tid];

  if (t < 36) {
#pragma unroll
    for (int k = 0; k < 5; ++k)
      p[g][k][t / 6][t % 6] = S[((size_t)b * 5 + k) * 36 + t];
  }
  __syncthreads();

  if (t < 30) {
    int k = t / 6, c = t % 6;
    float v[6];
#pragma unroll
    for (int d = 0; d < 6; ++d) v[d] = p[g][k][c][d];
    float mx = v[0];
#pragma unroll
    for (int d = 1; d < 6; ++d) mx = fmaxf(mx, v[d]);
    float s = 0.f;
#pragma unroll
    for (int d = 0; d < 6; ++d) { v[d] = expf(v[d] - mx); s += v[d]; }
    float inv = 1.f / s;
#pragma unroll
    for (int d = 0; d < 6; ++d) p[g][k][c][d] = v[d] * inv;
  }
  __syncthreads();

  if (t < 6) {
    int c = t;
    float ap[6];
#pragma unroll
    for (int j = 0; j < 6; ++j) ap[j] = lbv[j];
    for (int k = 0; k < 5; ++k)
#pragma unroll
      for (int d = 0; d < 6; ++d) {
        float pv = p[g][k][c][d];
#pragma unroll
        for (int j = 0; j < 6; ++j) ap[j] += pv * lw[k * 6 + d][j];
      }
    float mx = ap[0];
#pragma unroll
    for (int j = 1; j < 6; ++j) mx = fmaxf(mx, ap[j]);
    float s = 0.f;
#pragma unroll
    for (int j = 0; j < 6; ++j) { ap[j] = expf(ap[j] - mx); s += ap[j]; }
    float inv = 1.f / s;
#pragma unroll
    for (int j = 0; j < 6; ++j) {
      float a = ap[j] * inv;
      Ar[g][c][j] = a;
      Afull[(size_t)b * 36 + c * 6 + j] = a;
    }
  }
  __syncthreads();

  const int r6 = b * 6;
  short* xp = (short*)Xb;
#pragma unroll
  for (int it = 0; it < 2; ++it) {
    int c8 = (it * 64 + t) * 8;
    s16x8 xv[6];
#pragma unroll
    for (int d = 0; d < 6; ++d)
      xv[d] = *(const s16x8*)(xp + ((size_t)r6 + d) * 1024 + c8);
#pragma unroll
    for (int c = 0; c < 6; ++c) {
      s16x8 o;
#pragma unroll
      for (int e = 0; e < 8; ++e) {
        float s = 0.f;
#pragma unroll
        for (int d = 0; d < 6; ++d) s += Ar[g][c][d] * s2f(xv[d][e]);
        o[e] = f2s(s);
      }
      *(s16x8*)(xp + ((size_t)r6 + c) * 1024 + c8) = o;
    }
  }
}

// ---------------------------------------------------------------------------
// batch_out4: 4 batches per 256-thr block. out(f32) = BN2(A @ hw + gb2)
// ---------------------------------------------------------------------------
__global__ __launch_bounds__(256) void batch_out4(
    const float* __restrict__ Afull, const bf16* __restrict__ HW,
    const float* __restrict__ gb2,
    const float* __restrict__ g2, const float* __restrict__ b2,
    const float* __restrict__ m2, const float* __restrict__ v2,
    float* __restrict__ out) {
  const int tid = threadIdx.x, g = tid >> 6, t = tid & 63;
  const int b = blockIdx.x * 4 + g;
  __shared__ float Ar[4][36];
  __shared__ float sc[6], sm[6], sb[6];
  if (t < 36) Ar[g][t] = Afull[(size_t)b * 36 + t];
  if (tid < 6) {
    sc[tid] = g2[tid] * rsqrtf(v2[tid] + 1e-5f);
    sm[tid] = m2[tid];
    sb[tid] = b2[tid];
  }
  __syncthreads();
  for (int col = t; col < 256; col += 64) {
    float hw[6];
#pragma unroll
    for (int d = 0; d < 6; ++d) hw[d] = s2f(((const short*)HW)[((size_t)b * 6 + d) * 256 + col]);
    float gv = gb2[col];
#pragma unroll
    for (int c = 0; c < 6; ++c) {
      float o = gv;
#pragma unroll
      for (int d = 0; d < 6; ++d) o += Ar[g][c * 6 + d] * hw[d];
      o = (o - sm[c]) * sc[c] + sb[c];
      out[((size_t)b * 6 + c) * 256 + col] = o;
    }
  }
}

// ---------------------------------------------------------------------------
extern "C" void kernel_launch(void* const* d_in, const int* in_sizes, int n_in,
                              void* d_out, int out_size, void* d_ws, size_t ws_size,
                              hipStream_t stream) {
  const float* x    = (const float*)d_in[0];
  const float* aW1  = (const float*)d_in[1];
  const float* ab1  = (const float*)d_in[2];
  const float* aW2  = (const float*)d_in[3];
  const float* ab2  = (const float*)d_in[4];
  const float* linW = (const float*)d_in[5];
  const float* linb = (const float*)d_in[6];
  const float* gW1  = (const float*)d_in[7];
  const float* gb1  = (const float*)d_in[8];
  const float* gW2  = (const float*)d_in[9];
  const float* gb2  = (const float*)d_in[10];
  const float* prelu = (const float*)d_in[11];
  const float* bn1g = (const float*)d_in[12];
  const float* bn1b = (const float*)d_in[13];
  const float* bn1m = (const float*)d_in[14];
  const float* bn1v = (const float*)d_in[15];
  const float* bn2g = (const float*)d_in[16];
  const float* bn2b = (const float*)d_in[17];
  const float* bn2m = (const float*)d_in[18];
  const float* bn2v = (const float*)d_in[19];

  char* ws = (char*)d_ws;
  bf16* W1T = (bf16*)(ws + 0);           // 5 x 512 x 1024
  bf16* W2T = (bf16*)(ws + 5242880);     // 5 x 512 x 1024
  bf16* G1T = (bf16*)(ws + 10485760);    // 512 x 1024
  bf16* G2T = (bf16*)(ws + 11534336);    // 256 x 512
  float* S  = (float*)(ws + 11796480);   // 4096 x 5 x 36 (fallback only)
  float* Af = (float*)(ws + 14745600);   // 4096 x 36
  bf16* Xb  = (bf16*)(ws + 15335424);    // 24576 x 1024 (x bf16, then Xa=A@x)
#define PANEL(i) ((bf16*)(ws + 65667072 + (size_t)(i) * 25165824))  // 24576x512
  const bool big5 = ws_size >= 292159488ull;  // P8 exists
  // ws >= 266993664 (P0..P7 + Xb) proven by R9's big3 run.

  prep_kernel<<<18048, 256, 0, stream>>>(x, Xb, aW1, W1T, aW2, W2T, gW1, G1T, gW2, G2T);

  GJobs10 J{};

  if (big5) {
    // ---- ONE Q/KV dispatch: 10 slices (1920 blocks = 7.5 rounds) ----
    for (int h = 0; h < 4; ++h) {
      J.j[2 * h]     = GJob{W1T + (size_t)h * 524288, ab1, h * 512, PANEL(2 * h)};
      J.j[2 * h + 1] = GJob{W2T + (size_t)h * 524288, ab2, h * 512, PANEL(2 * h + 1)};
    }
    J.j[8] = GJob{W1T + 4 * 524288, ab1, 2048, (bf16*)d_out};  // Q4 -> d_out scratch
    J.j[9] = GJob{W2T + 4 * 524288, ab2, 2048, PANEL(8)};      // KV4
    gemm256_8ph<<<dim3(96, 2, 10), 512, 0, stream>>>(
        Xb, J, -1, nullptr, nullptr, nullptr, nullptr, nullptr, 24576, 512, 1024);

    // ---- mid: parallel scores (12 waves) + softmaxes + A + Xa in-place ----
    mid5p<<<1024, 1024, 0, stream>>>(
        PANEL(0), PANEL(2), PANEL(4), PANEL(6),
        PANEL(1), PANEL(3), PANEL(5), PANEL(7),
        (const bf16*)d_out, PANEL(8), Xb, linW, linb, Af);

    // ---- H' = Xa @ gW1 with fused gb1 + PReLU + BN1 -> P0 ----
    GJobs10 JH{};
    JH.j[0] = GJob{G1T, gb1, 0, PANEL(0)};
    gemm256_8ph<<<dim3(96, 2, 1), 512, 0, stream>>>(
        Xb, JH, 0, prelu, bn1g, bn1b, bn1m, bn1v, 24576, 512, 1024);

    // ---- HW = H @ gW2 -> P1 ----
    gemm_bt<0><<<dim3(192, 2, 1), 256, 0, stream>>>(
        PANEL(0), G2T, G2T, nullptr, nullptr, 0, PANEL(1), PANEL(1), 24576, 256, 512);

    batch_out4<<<1024, 256, 0, stream>>>(Af, PANEL(1), gb2, bn2g, bn2b, bn2m, bn2v,
                                         (float*)d_out);
  } else {
    // ---- fallback (proven ws >= 267 MB): pairs + standalone scores ----
    for (int h = 0; h < 2; ++h) {
      J.j[2 * h]     = GJob{W1T + (size_t)h * 524288, ab1, h * 512, PANEL(2 * h)};
      J.j[2 * h + 1] = GJob{W2T + (size_t)h * 524288, ab2, h * 512, PANEL(2 * h + 1)};
    }
    gemm256_8ph<<<dim3(96, 2, 4), 512, 0, stream>>>(
        Xb, J, -1, nullptr, nullptr, nullptr, nullptr, nullptr, 24576, 512, 1024);
    scores_mfma2<<<dim3(512, 2), 256, 0, stream>>>(
        PANEL(0), PANEL(1), PANEL(2), PANEL(3), S, 0);

    for (int h = 0; h < 2; ++h) {
      J.j[2 * h]     = GJob{W1T + (size_t)(h + 2) * 524288, ab1, (h + 2) * 512, PANEL(4 + 2 * h)};
      J.j[2 * h + 1] = GJob{W2T + (size_t)(h + 2) * 524288, ab2, (h + 2) * 512, PANEL(5 + 2 * h)};
    }
    gemm256_8ph<<<dim3(96, 2, 4), 512, 0, stream>>>(
        Xb, J, -1, nullptr, nullptr, nullptr, nullptr, nullptr, 24576, 512, 1024);
    scores_mfma2<<<dim3(512, 2), 256, 0, stream>>>(
        PANEL(4), PANEL(5), PANEL(6), PANEL(7), S, 2);

    J.j[0] = GJob{W1T + 4 * 524288, ab1, 2048, PANEL(0)};
    J.j[1] = GJob{W2T + 4 * 524288, ab2, 2048, PANEL(1)};
    gemm256_8ph<<<dim3(96, 2, 2), 512, 0, stream>>>(
        Xb, J, -1, nullptr, nullptr, nullptr, nullptr, nullptr, 24576, 512, 1024);
    scores_mfma2<<<dim3(512, 1), 256, 0, stream>>>(
        PANEL(0), PANEL(1), PANEL(0), PANEL(1), S, 4);

    mid_ax<<<1024, 256, 0, stream>>>(S, Xb, linW, linb, Af);

    GJobs10 JH{};
    JH.j[0] = GJob{G1T, gb1, 0, PANEL(2)};
    gemm256_8ph<<<dim3(96, 2, 1), 512, 0, stream>>>(
        Xb, JH, 0, prelu, bn1g, bn1b, bn1m, bn1v, 24576, 512, 1024);

    gemm_bt<0><<<dim3(192, 2, 1), 256, 0, stream>>>(
        PANEL(2), G2T, G2T, nullptr, nullptr, 0, PANEL(3), PANEL(3), 24576, 256, 512);

    batch_out4<<<1024, 256, 0, stream>>>(Af, PANEL(3), gb2, bn2g, bn2b, bn2m, bn2v,
                                         (float*)d_out);
  }
#undef PANEL
}